// Round 6
// baseline (693.400 us; speedup 1.0000x reference)
//
#include <hip/hip_runtime.h>
#include <stdint.h>

typedef __bf16 bf16;
typedef __bf16 bf16x8 __attribute__((ext_vector_type(8)));
typedef float f32x4 __attribute__((ext_vector_type(4)));

#define AS1 __attribute__((address_space(1)))
#define AS3 __attribute__((address_space(3)))

// x: [4,2048,1024] f32, W: [1024,3072] f32, out: [4,2048,1024] f32
// ws: xb[8192][1024]bf16 @0; wt[3072][1024]bf16 @16777216; kb @23068672;
//     qb @39845888 (pre-scaled log2e/32); vt[64][64][2048] @56623104
// Base-2 softmax (log2e folded into qb + ALiBi slope).

__global__ void cvt_x_kernel(const float* __restrict__ x, bf16* __restrict__ xb) {
    int i = blockIdx.x * 256 + threadIdx.x;
    const float4* x4 = (const float4*)x;
    float4 a = x4[i * 2];
    float4 b = x4[i * 2 + 1];
    bf16x8 o;
    o[0] = (bf16)a.x; o[1] = (bf16)a.y; o[2] = (bf16)a.z; o[3] = (bf16)a.w;
    o[4] = (bf16)b.x; o[5] = (bf16)b.y; o[6] = (bf16)b.z; o[7] = (bf16)b.w;
    *(bf16x8*)(xb + (size_t)i * 8) = o;
}

__global__ void cvt_w_kernel(const float* __restrict__ w, bf16* __restrict__ wt) {
    __shared__ float tile[32][33];
    int nt = blockIdx.x, kt = blockIdx.y;
    int tx = threadIdx.x, ty = threadIdx.y;
#pragma unroll
    for (int j = 0; j < 4; ++j)
        tile[ty + j * 8][tx] = w[(size_t)(kt * 32 + ty + j * 8) * 3072 + nt * 32 + tx];
    __syncthreads();
#pragma unroll
    for (int j = 0; j < 4; ++j)
        wt[(size_t)(nt * 32 + ty + j * 8) * 1024 + kt * 32 + tx] = (bf16)tile[tx][ty + j * 8];
}

// ---------------- GEMM: kqv = xb @ wt^T, scatter to kb/qb/vt ----------------
__global__ __launch_bounds__(256) void gemm_kqv_kernel(
    const bf16* __restrict__ xb, const bf16* __restrict__ wt,
    bf16* __restrict__ kb, bf16* __restrict__ qb, bf16* __restrict__ vt) {
    __shared__ bf16 As[2][128 * 32];
    __shared__ bf16 Bs[2][128 * 32];
    int bid = blockIdx.x;
    int bm = bid / 24, bn = bid % 24;
    int m0 = bm * 128, n0 = bn * 128;
    int t = threadIdx.x;
    int lane = t & 63, wid = t >> 6;
    int g = lane >> 4, l15 = lane & 15;
    int wr = wid >> 1, wc = wid & 1;

    f32x4 acc[4][4] = {};

    auto stageAB = [&](int ks, int buf) {
        int k0 = ks * 32;
#pragma unroll
        for (int c = 0; c < 2; ++c) {
            int slot = c * 256 + t;
            int row = slot >> 2, kk = (slot & 3) * 8;
            __builtin_amdgcn_global_load_lds(
                (const AS1 void*)(xb + (size_t)(m0 + row) * 1024 + k0 + kk),
                (AS3 void*)(&As[buf][slot * 8]), 16, 0, 0);
        }
#pragma unroll
        for (int c = 0; c < 2; ++c) {
            int slot = c * 256 + t;
            int row = slot >> 2, kk = (slot & 3) * 8;
            __builtin_amdgcn_global_load_lds(
                (const AS1 void*)(wt + (size_t)(n0 + row) * 1024 + k0 + kk),
                (AS3 void*)(&Bs[buf][slot * 8]), 16, 0, 0);
        }
    };

    stageAB(0, 0);
    for (int ks = 0; ks < 32; ++ks) {
        __syncthreads();
        if (ks + 1 < 32) stageAB(ks + 1, (ks + 1) & 1);
        const bf16* Ab = As[ks & 1];
        const bf16* Bb = Bs[ks & 1];
        bf16x8 af[4], bfr[4];
#pragma unroll
        for (int mi = 0; mi < 4; ++mi)
            af[mi] = *(const bf16x8*)(Ab + (wr * 64 + mi * 16 + l15) * 32 + g * 8);
#pragma unroll
        for (int ni = 0; ni < 4; ++ni)
            bfr[ni] = *(const bf16x8*)(Bb + (wc * 64 + ni * 16 + l15) * 32 + g * 8);
#pragma unroll
        for (int mi = 0; mi < 4; ++mi)
#pragma unroll
            for (int ni = 0; ni < 4; ++ni)
                acc[mi][ni] = __builtin_amdgcn_mfma_f32_16x16x32_bf16(
                    af[mi], bfr[ni], acc[mi][ni], 0, 0, 0);
    }

    int tsel = n0 >> 10;
#pragma unroll
    for (int mi = 0; mi < 4; ++mi) {
#pragma unroll
        for (int ni = 0; ni < 4; ++ni) {
#pragma unroll
            for (int r = 0; r < 4; ++r) {
                int row = m0 + wr * 64 + mi * 16 + g * 4 + r;
                int col = n0 + wc * 64 + ni * 16 + l15;
                int b = row >> 11, s = row & 2047;
                int cc = col & 1023;
                int h = cc >> 6, d = cc & 63;
                int bh = b * 16 + h;
                float v = acc[mi][ni][r];
                if (tsel == 0)      kb[((size_t)bh * 2048 + s) * 64 + d] = (bf16)v;
                else if (tsel == 1) qb[((size_t)bh * 2048 + s) * 64 + d] = (bf16)(v * 0.0450842503f);
                else                vt[((size_t)bh * 64 + d) * 2048 + s] = (bf16)v;
            }
        }
    }
}

// ---------------- Flash attention with ALiBi (base-2 softmax) ----------------
// LDS 40KB (K single-buffered, V double, P wave-private) -> 4 blocks/CU.
// 2 barriers/iter: b1 (loads of tile t drained), b2 (K reads done -> restage).
__global__ __launch_bounds__(256, 4) void attn_kernel(
    const bf16* __restrict__ qb, const bf16* __restrict__ kb,
    const bf16* __restrict__ vt, float* __restrict__ out) {
    __shared__ bf16 Kl[64 * 64];
    __shared__ bf16 Vl[2][64 * 64];
    __shared__ bf16 Pl[4][32 * 64];
    int bid = blockIdx.x;
    int bh = bid >> 4, qt = bid & 15;
    int b = bh >> 4, h = bh & 15;
    int t = threadIdx.x, lane = t & 63, wid = t >> 6;
    int g = lane >> 4, l15 = lane & 15;
    int q0 = qt * 128 + wid * 32;
    float mh2 = exp2f(-0.5f * (float)(h + 1)) * 1.44269504f;

    const bf16* Qp = qb + ((size_t)bh * 2048 + q0) * 64;
    const bf16* Kp = kb + (size_t)bh * 2048 * 64;
    const bf16* Vp = vt + (size_t)bh * 64 * 2048;

    bf16x8 qf[2][2];
#pragma unroll
    for (int qi = 0; qi < 2; ++qi)
#pragma unroll
        for (int kk = 0; kk < 2; ++kk)
            qf[qi][kk] = *(const bf16x8*)(Qp + (size_t)(qi * 16 + l15) * 64 + kk * 32 + g * 8);

    f32x4 oacc[2][4] = {};
    float mrun[2][4], lrun[2][4];
#pragma unroll
    for (int qi = 0; qi < 2; ++qi)
#pragma unroll
        for (int r = 0; r < 4; ++r) { mrun[qi][r] = -3.0e38f; lrun[qi][r] = 0.f; }

    float colb[4];
#pragma unroll
    for (int ji = 0; ji < 4; ++ji) colb[ji] = mh2 * (float)(ji * 16 + l15);

    auto stageK = [&](int tile) {
        int j0 = tile * 64;
#pragma unroll
        for (int c = 0; c < 2; ++c) {
            int slot = c * 256 + t;
            int row = slot >> 3;
            int cs = (slot & 7) ^ (row & 7);
            __builtin_amdgcn_global_load_lds(
                (const AS1 void*)(Kp + (size_t)(j0 + row) * 64 + cs * 8),
                (AS3 void*)(&Kl[slot * 8]), 16, 0, 0);
        }
    };
    auto stageV = [&](int tile, int buf) {
        int j0 = tile * 64;
#pragma unroll
        for (int c = 0; c < 2; ++c) {
            int slot = c * 256 + t;
            int row = slot >> 3;
            int cs = (slot & 7) ^ (row & 7);
            __builtin_amdgcn_global_load_lds(
                (const AS1 void*)(Vp + (size_t)row * 2048 + j0 + cs * 8),
                (AS3 void*)(&Vl[buf][slot * 8]), 16, 0, 0);
        }
    };

    stageK(0);
    stageV(0, 0);
    bf16* Pw = Pl[wid];

    for (int tile = 0; tile < 32; ++tile) {
        __syncthreads();                 // b1: K[t],V[t] staged data drained
        const bf16* Vb = Vl[tile & 1];

        // S2 = (Q*log2e/32) K^T
        f32x4 sc[2][4] = {};
#pragma unroll
        for (int ji = 0; ji < 4; ++ji) {
#pragma unroll
            for (int kk = 0; kk < 2; ++kk) {
                int row = ji * 16 + l15;
                int c16 = (kk * 4 + g) ^ (row & 7);
                bf16x8 kf = *(const bf16x8*)(Kl + row * 64 + c16 * 8);
#pragma unroll
                for (int qi = 0; qi < 2; ++qi)
                    sc[qi][ji] = __builtin_amdgcn_mfma_f32_16x16x32_bf16(
                        qf[qi][kk], kf, sc[qi][ji], 0, 0, 0);
            }
        }
        __syncthreads();                 // b2: all waves done reading Kl
        if (tile + 1 < 32) {
            stageK(tile + 1);            // window: softmax+P+PV of this tile
            stageV(tile + 1, (tile + 1) & 1);
        }

        // + ALiBi*log2e (only the m*j term; -m*i is softmax-invariant)
        float tb = mh2 * (float)(tile * 64);
        float pmx[2][4];
#pragma unroll
        for (int qi = 0; qi < 2; ++qi) {
#pragma unroll
            for (int ji = 0; ji < 4; ++ji) {
                float add = tb + colb[ji];
#pragma unroll
                for (int r = 0; r < 4; ++r) sc[qi][ji][r] += add;
            }
#pragma unroll
            for (int r = 0; r < 4; ++r)
                pmx[qi][r] = fmaxf(fmaxf(sc[qi][0][r], sc[qi][1][r]),
                                   fmaxf(sc[qi][2][r], sc[qi][3][r]));
        }

        // defer-max: if no row's in-lane partial max grew past mrun+8 anywhere
        // in the wave, skip max-reduce and rescale entirely (P bounded by 2^8).
        int stable = 1;
#pragma unroll
        for (int qi = 0; qi < 2; ++qi)
#pragma unroll
            for (int r = 0; r < 4; ++r)
                stable &= (pmx[qi][r] <= mrun[qi][r] + 8.0f) ? 1 : 0;
        if (!__all(stable)) {
#pragma unroll
            for (int qi = 0; qi < 2; ++qi)
#pragma unroll
                for (int r = 0; r < 4; ++r) {
                    float mx = pmx[qi][r];
#pragma unroll
                    for (int m = 1; m < 16; m <<= 1) mx = fmaxf(mx, __shfl_xor(mx, m));
                    float mnew = fmaxf(mrun[qi][r], mx);
                    float corr = __builtin_amdgcn_exp2f(mrun[qi][r] - mnew);
                    mrun[qi][r] = mnew;
                    lrun[qi][r] *= corr;
#pragma unroll
                    for (int di = 0; di < 4; ++di) oacc[qi][di][r] *= corr;
                }
        }

        // p = exp2(s - m); row-sum
#pragma unroll
        for (int qi = 0; qi < 2; ++qi)
#pragma unroll
            for (int r = 0; r < 4; ++r) {
                float mnew = mrun[qi][r];
                float sum = 0.f;
#pragma unroll
                for (int ji = 0; ji < 4; ++ji) {
                    float p = __builtin_amdgcn_exp2f(sc[qi][ji][r] - mnew);
                    sc[qi][ji][r] = p;
                    sum += p;
                }
#pragma unroll
                for (int m = 1; m < 16; m <<= 1) sum += __shfl_xor(sum, m);
                lrun[qi][r] += sum;
            }

        // P -> wave-private LDS (bf16, swizzled), reload as A-fragments
#pragma unroll
        for (int qi = 0; qi < 2; ++qi)
#pragma unroll
            for (int r = 0; r < 4; ++r) {
                int row = qi * 16 + g * 4 + r;
                int rs = row & 7;
#pragma unroll
                for (int ji = 0; ji < 4; ++ji) {
                    int col = ji * 16 + l15;
                    int addr = row * 64 + (((col >> 3) ^ rs) * 8) + (col & 7);
                    Pw[addr] = (bf16)sc[qi][ji][r];
                }
            }

        // O += P @ V
#pragma unroll
        for (int kk = 0; kk < 2; ++kk) {
            bf16x8 pf[2];
#pragma unroll
            for (int qi = 0; qi < 2; ++qi) {
                int row = qi * 16 + l15;
                int c16 = (kk * 4 + g) ^ (row & 7);
                pf[qi] = *(const bf16x8*)(Pw + row * 64 + c16 * 8);
            }
#pragma unroll
            for (int di = 0; di < 4; ++di) {
                int row = di * 16 + l15;
                int c16 = (kk * 4 + g) ^ (row & 7);
                bf16x8 vf = *(const bf16x8*)(Vb + row * 64 + c16 * 8);
#pragma unroll
                for (int qi = 0; qi < 2; ++qi)
                    oacc[qi][di] = __builtin_amdgcn_mfma_f32_16x16x32_bf16(
                        pf[qi], vf, oacc[qi][di], 0, 0, 0);
            }
        }
    }

#pragma unroll
    for (int qi = 0; qi < 2; ++qi) {
#pragma unroll
        for (int r = 0; r < 4; ++r) {
            float inv = 1.0f / lrun[qi][r];
            int s = q0 + qi * 16 + g * 4 + r;
            float* op = out + ((size_t)b * 2048 + s) * 1024 + h * 64;
#pragma unroll
            for (int di = 0; di < 4; ++di)
                op[di * 16 + l15] = oacc[qi][di][r] * inv;
        }
    }
}

extern "C" void kernel_launch(void* const* d_in, const int* in_sizes, int n_in,
                              void* d_out, int out_size, void* d_ws, size_t ws_size,
                              hipStream_t stream) {
    (void)in_sizes; (void)n_in; (void)out_size; (void)ws_size;
    const float* x = (const float*)d_in[0];
    const float* w = (const float*)d_in[1];
    float* out = (float*)d_out;
    char* ws = (char*)d_ws;
    bf16* xb = (bf16*)(ws);
    bf16* wt = (bf16*)(ws + 16777216);
    bf16* kb = (bf16*)(ws + 23068672);
    bf16* qb = (bf16*)(ws + 39845888);
    bf16* vt = (bf16*)(ws + 56623104);

    cvt_x_kernel<<<4096, 256, 0, stream>>>(x, xb);
    cvt_w_kernel<<<dim3(96, 32), dim3(32, 8), 0, stream>>>(w, wt);
    gemm_kqv_kernel<<<1536, 256, 0, stream>>>(xb, wt, kb, qb, vt);
    attn_kernel<<<1024, 256, 0, stream>>>(qb, kb, vt, out);
}

// Round 7
// 376.336 us; speedup vs baseline: 1.8425x; 1.8425x over previous
//
#include <hip/hip_runtime.h>
#include <stdint.h>

typedef __bf16 bf16;
typedef __bf16 bf16x8 __attribute__((ext_vector_type(8)));
typedef float f32x4 __attribute__((ext_vector_type(4)));

#define AS1 __attribute__((address_space(1)))
#define AS3 __attribute__((address_space(3)))

// x: [4,2048,1024] f32, W: [1024,3072] f32, out: [4,2048,1024] f32
// ws: xb[8192][1024]bf16 @0; wt[3072][1024]bf16 @16777216; kb @23068672;
//     qb @39845888 (pre-scaled log2e/32); vt[64][64][2048] @56623104
// Base-2 softmax (log2e folded into qb + ALiBi slope).

__global__ void cvt_x_kernel(const float* __restrict__ x, bf16* __restrict__ xb) {
    int i = blockIdx.x * 256 + threadIdx.x;
    const float4* x4 = (const float4*)x;
    float4 a = x4[i * 2];
    float4 b = x4[i * 2 + 1];
    bf16x8 o;
    o[0] = (bf16)a.x; o[1] = (bf16)a.y; o[2] = (bf16)a.z; o[3] = (bf16)a.w;
    o[4] = (bf16)b.x; o[5] = (bf16)b.y; o[6] = (bf16)b.z; o[7] = (bf16)b.w;
    *(bf16x8*)(xb + (size_t)i * 8) = o;
}

__global__ void cvt_w_kernel(const float* __restrict__ w, bf16* __restrict__ wt) {
    __shared__ float tile[32][33];
    int nt = blockIdx.x, kt = blockIdx.y;
    int tx = threadIdx.x, ty = threadIdx.y;
#pragma unroll
    for (int j = 0; j < 4; ++j)
        tile[ty + j * 8][tx] = w[(size_t)(kt * 32 + ty + j * 8) * 3072 + nt * 32 + tx];
    __syncthreads();
#pragma unroll
    for (int j = 0; j < 4; ++j)
        wt[(size_t)(nt * 32 + ty + j * 8) * 1024 + kt * 32 + tx] = (bf16)tile[tx][ty + j * 8];
}

// ---------------- GEMM: kqv = xb @ wt^T, scatter to kb/qb/vt ----------------
__global__ __launch_bounds__(256) void gemm_kqv_kernel(
    const bf16* __restrict__ xb, const bf16* __restrict__ wt,
    bf16* __restrict__ kb, bf16* __restrict__ qb, bf16* __restrict__ vt) {
    __shared__ bf16 As[2][128 * 32];
    __shared__ bf16 Bs[2][128 * 32];
    int bid = blockIdx.x;
    int bm = bid / 24, bn = bid % 24;
    int m0 = bm * 128, n0 = bn * 128;
    int t = threadIdx.x;
    int lane = t & 63, wid = t >> 6;
    int g = lane >> 4, l15 = lane & 15;
    int wr = wid >> 1, wc = wid & 1;

    f32x4 acc[4][4] = {};

    auto stageAB = [&](int ks, int buf) {
        int k0 = ks * 32;
#pragma unroll
        for (int c = 0; c < 2; ++c) {
            int slot = c * 256 + t;
            int row = slot >> 2, kk = (slot & 3) * 8;
            __builtin_amdgcn_global_load_lds(
                (const AS1 void*)(xb + (size_t)(m0 + row) * 1024 + k0 + kk),
                (AS3 void*)(&As[buf][slot * 8]), 16, 0, 0);
        }
#pragma unroll
        for (int c = 0; c < 2; ++c) {
            int slot = c * 256 + t;
            int row = slot >> 2, kk = (slot & 3) * 8;
            __builtin_amdgcn_global_load_lds(
                (const AS1 void*)(wt + (size_t)(n0 + row) * 1024 + k0 + kk),
                (AS3 void*)(&Bs[buf][slot * 8]), 16, 0, 0);
        }
    };

    stageAB(0, 0);
    for (int ks = 0; ks < 32; ++ks) {
        __syncthreads();
        if (ks + 1 < 32) stageAB(ks + 1, (ks + 1) & 1);
        const bf16* Ab = As[ks & 1];
        const bf16* Bb = Bs[ks & 1];
        bf16x8 af[4], bfr[4];
#pragma unroll
        for (int mi = 0; mi < 4; ++mi)
            af[mi] = *(const bf16x8*)(Ab + (wr * 64 + mi * 16 + l15) * 32 + g * 8);
#pragma unroll
        for (int ni = 0; ni < 4; ++ni)
            bfr[ni] = *(const bf16x8*)(Bb + (wc * 64 + ni * 16 + l15) * 32 + g * 8);
#pragma unroll
        for (int mi = 0; mi < 4; ++mi)
#pragma unroll
            for (int ni = 0; ni < 4; ++ni)
                acc[mi][ni] = __builtin_amdgcn_mfma_f32_16x16x32_bf16(
                    af[mi], bfr[ni], acc[mi][ni], 0, 0, 0);
    }

    int tsel = n0 >> 10;
#pragma unroll
    for (int mi = 0; mi < 4; ++mi) {
#pragma unroll
        for (int ni = 0; ni < 4; ++ni) {
#pragma unroll
            for (int r = 0; r < 4; ++r) {
                int row = m0 + wr * 64 + mi * 16 + g * 4 + r;
                int col = n0 + wc * 64 + ni * 16 + l15;
                int b = row >> 11, s = row & 2047;
                int cc = col & 1023;
                int h = cc >> 6, d = cc & 63;
                int bh = b * 16 + h;
                float v = acc[mi][ni][r];
                if (tsel == 0)      kb[((size_t)bh * 2048 + s) * 64 + d] = (bf16)v;
                else if (tsel == 1) qb[((size_t)bh * 2048 + s) * 64 + d] = (bf16)(v * 0.0450842503f);
                else                vt[((size_t)bh * 64 + d) * 2048 + s] = (bf16)v;
            }
        }
    }
}

// ---------------- Flash attention with ALiBi (base-2 softmax) ----------------
// LDS 40KB (K single-buffered, V double, P wave-private) -> 4 blocks/CU by LDS.
// NO min-waves launch-bounds arg: VGPR ~108 naturally allows 4 waves/SIMD;
// capping to 64 VGPR caused massive scratch spill (955MB FETCH, 2x dur).
__global__ __launch_bounds__(256) void attn_kernel(
    const bf16* __restrict__ qb, const bf16* __restrict__ kb,
    const bf16* __restrict__ vt, float* __restrict__ out) {
    __shared__ bf16 Kl[64 * 64];
    __shared__ bf16 Vl[2][64 * 64];
    __shared__ bf16 Pl[4][32 * 64];
    int bid = blockIdx.x;
    int bh = bid >> 4, qt = bid & 15;
    int b = bh >> 4, h = bh & 15;
    int t = threadIdx.x, lane = t & 63, wid = t >> 6;
    int g = lane >> 4, l15 = lane & 15;
    int q0 = qt * 128 + wid * 32;
    float mh2 = exp2f(-0.5f * (float)(h + 1)) * 1.44269504f;

    const bf16* Qp = qb + ((size_t)bh * 2048 + q0) * 64;
    const bf16* Kp = kb + (size_t)bh * 2048 * 64;
    const bf16* Vp = vt + (size_t)bh * 64 * 2048;

    bf16x8 qf[2][2];
#pragma unroll
    for (int qi = 0; qi < 2; ++qi)
#pragma unroll
        for (int kk = 0; kk < 2; ++kk)
            qf[qi][kk] = *(const bf16x8*)(Qp + (size_t)(qi * 16 + l15) * 64 + kk * 32 + g * 8);

    f32x4 oacc[2][4] = {};
    float mrun[2][4], lrun[2][4];
#pragma unroll
    for (int qi = 0; qi < 2; ++qi)
#pragma unroll
        for (int r = 0; r < 4; ++r) { mrun[qi][r] = -3.0e38f; lrun[qi][r] = 0.f; }

    float colb[4];
#pragma unroll
    for (int ji = 0; ji < 4; ++ji) colb[ji] = mh2 * (float)(ji * 16 + l15);

    auto stageK = [&](int tile) {
        int j0 = tile * 64;
#pragma unroll
        for (int c = 0; c < 2; ++c) {
            int slot = c * 256 + t;
            int row = slot >> 3;
            int cs = (slot & 7) ^ (row & 7);
            __builtin_amdgcn_global_load_lds(
                (const AS1 void*)(Kp + (size_t)(j0 + row) * 64 + cs * 8),
                (AS3 void*)(&Kl[slot * 8]), 16, 0, 0);
        }
    };
    auto stageV = [&](int tile, int buf) {
        int j0 = tile * 64;
#pragma unroll
        for (int c = 0; c < 2; ++c) {
            int slot = c * 256 + t;
            int row = slot >> 3;
            int cs = (slot & 7) ^ (row & 7);
            __builtin_amdgcn_global_load_lds(
                (const AS1 void*)(Vp + (size_t)row * 2048 + j0 + cs * 8),
                (AS3 void*)(&Vl[buf][slot * 8]), 16, 0, 0);
        }
    };

    stageK(0);
    stageV(0, 0);
    bf16* Pw = Pl[wid];

    for (int tile = 0; tile < 32; ++tile) {
        __syncthreads();                 // b1: K[t],V[t] staged data drained
        const bf16* Vb = Vl[tile & 1];

        // S2 = (Q*log2e/32) K^T
        f32x4 sc[2][4] = {};
#pragma unroll
        for (int ji = 0; ji < 4; ++ji) {
#pragma unroll
            for (int kk = 0; kk < 2; ++kk) {
                int row = ji * 16 + l15;
                int c16 = (kk * 4 + g) ^ (row & 7);
                bf16x8 kf = *(const bf16x8*)(Kl + row * 64 + c16 * 8);
#pragma unroll
                for (int qi = 0; qi < 2; ++qi)
                    sc[qi][ji] = __builtin_amdgcn_mfma_f32_16x16x32_bf16(
                        qf[qi][kk], kf, sc[qi][ji], 0, 0, 0);
            }
        }
        __syncthreads();                 // b2: all waves done reading Kl
        if (tile + 1 < 32) {
            stageK(tile + 1);            // window: softmax+P+PV of this tile
            stageV(tile + 1, (tile + 1) & 1);
        }

        // + ALiBi*log2e (only the m*j term; -m*i is softmax-invariant)
        float tb = mh2 * (float)(tile * 64);
        float pmx[2][4];
#pragma unroll
        for (int qi = 0; qi < 2; ++qi) {
#pragma unroll
            for (int ji = 0; ji < 4; ++ji) {
                float add = tb + colb[ji];
#pragma unroll
                for (int r = 0; r < 4; ++r) sc[qi][ji][r] += add;
            }
#pragma unroll
            for (int r = 0; r < 4; ++r)
                pmx[qi][r] = fmaxf(fmaxf(sc[qi][0][r], sc[qi][1][r]),
                                   fmaxf(sc[qi][2][r], sc[qi][3][r]));
        }

        // defer-max: if no row's in-lane partial max grew past mrun+8 anywhere
        // in the wave, skip max-reduce and rescale entirely (P bounded by 2^8).
        int stable = 1;
#pragma unroll
        for (int qi = 0; qi < 2; ++qi)
#pragma unroll
            for (int r = 0; r < 4; ++r)
                stable &= (pmx[qi][r] <= mrun[qi][r] + 8.0f) ? 1 : 0;
        if (!__all(stable)) {
#pragma unroll
            for (int qi = 0; qi < 2; ++qi)
#pragma unroll
                for (int r = 0; r < 4; ++r) {
                    float mx = pmx[qi][r];
#pragma unroll
                    for (int m = 1; m < 16; m <<= 1) mx = fmaxf(mx, __shfl_xor(mx, m));
                    float mnew = fmaxf(mrun[qi][r], mx);
                    float corr = __builtin_amdgcn_exp2f(mrun[qi][r] - mnew);
                    mrun[qi][r] = mnew;
                    lrun[qi][r] *= corr;
#pragma unroll
                    for (int di = 0; di < 4; ++di) oacc[qi][di][r] *= corr;
                }
        }

        // p = exp2(s - m); row-sum
#pragma unroll
        for (int qi = 0; qi < 2; ++qi)
#pragma unroll
            for (int r = 0; r < 4; ++r) {
                float mnew = mrun[qi][r];
                float sum = 0.f;
#pragma unroll
                for (int ji = 0; ji < 4; ++ji) {
                    float p = __builtin_amdgcn_exp2f(sc[qi][ji][r] - mnew);
                    sc[qi][ji][r] = p;
                    sum += p;
                }
#pragma unroll
                for (int m = 1; m < 16; m <<= 1) sum += __shfl_xor(sum, m);
                lrun[qi][r] += sum;
            }

        // P -> wave-private LDS (bf16, swizzled), reload as A-fragments
#pragma unroll
        for (int qi = 0; qi < 2; ++qi)
#pragma unroll
            for (int r = 0; r < 4; ++r) {
                int row = qi * 16 + g * 4 + r;
                int rs = row & 7;
#pragma unroll
                for (int ji = 0; ji < 4; ++ji) {
                    int col = ji * 16 + l15;
                    int addr = row * 64 + (((col >> 3) ^ rs) * 8) + (col & 7);
                    Pw[addr] = (bf16)sc[qi][ji][r];
                }
            }

        // O += P @ V
#pragma unroll
        for (int kk = 0; kk < 2; ++kk) {
            bf16x8 pf[2];
#pragma unroll
            for (int qi = 0; qi < 2; ++qi) {
                int row = qi * 16 + l15;
                int c16 = (kk * 4 + g) ^ (row & 7);
                pf[qi] = *(const bf16x8*)(Pw + row * 64 + c16 * 8);
            }
#pragma unroll
            for (int di = 0; di < 4; ++di) {
                int row = di * 16 + l15;
                int c16 = (kk * 4 + g) ^ (row & 7);
                bf16x8 vf = *(const bf16x8*)(Vb + row * 64 + c16 * 8);
#pragma unroll
                for (int qi = 0; qi < 2; ++qi)
                    oacc[qi][di] = __builtin_amdgcn_mfma_f32_16x16x32_bf16(
                        pf[qi], vf, oacc[qi][di], 0, 0, 0);
            }
        }
    }

#pragma unroll
    for (int qi = 0; qi < 2; ++qi) {
#pragma unroll
        for (int r = 0; r < 4; ++r) {
            float inv = 1.0f / lrun[qi][r];
            int s = q0 + qi * 16 + g * 4 + r;
            float* op = out + ((size_t)b * 2048 + s) * 1024 + h * 64;
#pragma unroll
            for (int di = 0; di < 4; ++di)
                op[di * 16 + l15] = oacc[qi][di][r] * inv;
        }
    }
}

extern "C" void kernel_launch(void* const* d_in, const int* in_sizes, int n_in,
                              void* d_out, int out_size, void* d_ws, size_t ws_size,
                              hipStream_t stream) {
    (void)in_sizes; (void)n_in; (void)out_size; (void)ws_size;
    const float* x = (const float*)d_in[0];
    const float* w = (const float*)d_in[1];
    float* out = (float*)d_out;
    char* ws = (char*)d_ws;
    bf16* xb = (bf16*)(ws);
    bf16* wt = (bf16*)(ws + 16777216);
    bf16* kb = (bf16*)(ws + 23068672);
    bf16* qb = (bf16*)(ws + 39845888);
    bf16* vt = (bf16*)(ws + 56623104);

    cvt_x_kernel<<<4096, 256, 0, stream>>>(x, xb);
    cvt_w_kernel<<<dim3(96, 32), dim3(32, 8), 0, stream>>>(w, wt);
    gemm_kqv_kernel<<<1536, 256, 0, stream>>>(xb, wt, kb, qb, vt);
    attn_kernel<<<1024, 256, 0, stream>>>(qb, kb, vt, out);
}

// Round 9
// 311.740 us; speedup vs baseline: 2.2243x; 1.2072x over previous
//
#include <hip/hip_runtime.h>
#include <stdint.h>

typedef __bf16 bf16;
typedef __bf16 bf16x4 __attribute__((ext_vector_type(4)));
typedef __bf16 bf16x8 __attribute__((ext_vector_type(8)));
typedef float f32x4 __attribute__((ext_vector_type(4)));

#define AS1 __attribute__((address_space(1)))
#define AS3 __attribute__((address_space(3)))

// x: [4,2048,1024] f32, W: [1024,3072] f32, out: [4,2048,1024] f32
// ws: xb[8192][1024]bf16 @0; wt[3072][1024]bf16 @16777216; kb @23068672;
//     qb @39845888 (pre-scaled log2e/32); vt[64][64][2048] @56623104
// Base-2 softmax (log2e folded into qb + ALiBi slope).

__global__ void cvt_x_kernel(const float* __restrict__ x, bf16* __restrict__ xb) {
    int i = blockIdx.x * 256 + threadIdx.x;
    const float4* x4 = (const float4*)x;
    float4 a = x4[i * 2];
    float4 b = x4[i * 2 + 1];
    bf16x8 o;
    o[0] = (bf16)a.x; o[1] = (bf16)a.y; o[2] = (bf16)a.z; o[3] = (bf16)a.w;
    o[4] = (bf16)b.x; o[5] = (bf16)b.y; o[6] = (bf16)b.z; o[7] = (bf16)b.w;
    *(bf16x8*)(xb + (size_t)i * 8) = o;
}

__global__ void cvt_w_kernel(const float* __restrict__ w, bf16* __restrict__ wt) {
    __shared__ float tile[32][33];
    int nt = blockIdx.x, kt = blockIdx.y;
    int tx = threadIdx.x, ty = threadIdx.y;
#pragma unroll
    for (int j = 0; j < 4; ++j)
        tile[ty + j * 8][tx] = w[(size_t)(kt * 32 + ty + j * 8) * 3072 + nt * 32 + tx];
    __syncthreads();
#pragma unroll
    for (int j = 0; j < 4; ++j)
        wt[(size_t)(nt * 32 + ty + j * 8) * 1024 + kt * 32 + tx] = (bf16)tile[tx][ty + j * 8];
}

// ---------------- GEMM: kqv = xb @ wt^T, scatter to kb/qb/vt ----------------
__global__ __launch_bounds__(256) void gemm_kqv_kernel(
    const bf16* __restrict__ xb, const bf16* __restrict__ wt,
    bf16* __restrict__ kb, bf16* __restrict__ qb, bf16* __restrict__ vt) {
    __shared__ bf16 As[2][128 * 32];
    __shared__ bf16 Bs[2][128 * 32];
    int bid = blockIdx.x;
    int bm = bid / 24, bn = bid % 24;
    int m0 = bm * 128, n0 = bn * 128;
    int t = threadIdx.x;
    int lane = t & 63, wid = t >> 6;
    int g = lane >> 4, l15 = lane & 15;
    int wr = wid >> 1, wc = wid & 1;

    f32x4 acc[4][4] = {};

    auto stageAB = [&](int ks, int buf) {
        int k0 = ks * 32;
#pragma unroll
        for (int c = 0; c < 2; ++c) {
            int slot = c * 256 + t;
            int row = slot >> 2, kk = (slot & 3) * 8;
            __builtin_amdgcn_global_load_lds(
                (const AS1 void*)(xb + (size_t)(m0 + row) * 1024 + k0 + kk),
                (AS3 void*)(&As[buf][slot * 8]), 16, 0, 0);
        }
#pragma unroll
        for (int c = 0; c < 2; ++c) {
            int slot = c * 256 + t;
            int row = slot >> 2, kk = (slot & 3) * 8;
            __builtin_amdgcn_global_load_lds(
                (const AS1 void*)(wt + (size_t)(n0 + row) * 1024 + k0 + kk),
                (AS3 void*)(&Bs[buf][slot * 8]), 16, 0, 0);
        }
    };

    stageAB(0, 0);
    for (int ks = 0; ks < 32; ++ks) {
        __syncthreads();
        if (ks + 1 < 32) stageAB(ks + 1, (ks + 1) & 1);
        const bf16* Ab = As[ks & 1];
        const bf16* Bb = Bs[ks & 1];
        bf16x8 af[4], bfr[4];
#pragma unroll
        for (int mi = 0; mi < 4; ++mi)
            af[mi] = *(const bf16x8*)(Ab + (wr * 64 + mi * 16 + l15) * 32 + g * 8);
#pragma unroll
        for (int ni = 0; ni < 4; ++ni)
            bfr[ni] = *(const bf16x8*)(Bb + (wc * 64 + ni * 16 + l15) * 32 + g * 8);
#pragma unroll
        for (int mi = 0; mi < 4; ++mi)
#pragma unroll
            for (int ni = 0; ni < 4; ++ni)
                acc[mi][ni] = __builtin_amdgcn_mfma_f32_16x16x32_bf16(
                    af[mi], bfr[ni], acc[mi][ni], 0, 0, 0);
    }

    int tsel = n0 >> 10;
#pragma unroll
    for (int mi = 0; mi < 4; ++mi) {
#pragma unroll
        for (int ni = 0; ni < 4; ++ni) {
#pragma unroll
            for (int r = 0; r < 4; ++r) {
                int row = m0 + wr * 64 + mi * 16 + g * 4 + r;
                int col = n0 + wc * 64 + ni * 16 + l15;
                int b = row >> 11, s = row & 2047;
                int cc = col & 1023;
                int h = cc >> 6, d = cc & 63;
                int bh = b * 16 + h;
                float v = acc[mi][ni][r];
                if (tsel == 0)      kb[((size_t)bh * 2048 + s) * 64 + d] = (bf16)v;
                else if (tsel == 1) qb[((size_t)bh * 2048 + s) * 64 + d] = (bf16)(v * 0.0450842503f);
                else                vt[((size_t)bh * 64 + d) * 2048 + s] = (bf16)v;
            }
        }
    }
}

// ---------------- Flash attention with ALiBi (base-2, swapped QK^T) ----------
// S^T = mfma(K, Q): D[col=q=l15, row=j] -> each lane owns one q-row's 16 j's
// per qi; row-reduce = in-lane tree + 2 shfl_xor (g-quad). P written as b64
// chunks (contiguous j). O-layout (PV out) unchanged; lrun/corr bridged by
// one-off shfl broadcasts. LDS 40KB; no min-waves bound (spill hazard, r6).
__global__ __launch_bounds__(256) void attn_kernel(
    const bf16* __restrict__ qb, const bf16* __restrict__ kb,
    const bf16* __restrict__ vt, float* __restrict__ out) {
    __shared__ bf16 Kl[64 * 64];
    __shared__ bf16 Vl[2][64 * 64];
    __shared__ bf16 Pl[4][32 * 64];
    int bid = blockIdx.x;
    int bh = bid >> 4, qt = bid & 15;
    int b = bh >> 4, h = bh & 15;
    int t = threadIdx.x, lane = t & 63, wid = t >> 6;
    int g = lane >> 4, l15 = lane & 15;
    int q0 = qt * 128 + wid * 32;
    float mh2 = exp2f(-0.5f * (float)(h + 1)) * 1.44269504f;

    const bf16* Qp = qb + ((size_t)bh * 2048 + q0) * 64;
    const bf16* Kp = kb + (size_t)bh * 2048 * 64;
    const bf16* Vp = vt + (size_t)bh * 64 * 2048;

    // Q fragments (B-operand now; same lane mapping as A -> loads unchanged)
    bf16x8 qf[2][2];
#pragma unroll
    for (int qi = 0; qi < 2; ++qi)
#pragma unroll
        for (int kk = 0; kk < 2; ++kk)
            qf[qi][kk] = *(const bf16x8*)(Qp + (size_t)(qi * 16 + l15) * 64 + kk * 32 + g * 8);

    f32x4 oacc[2][4] = {};
    float mrun[2], lrun[2];
    mrun[0] = mrun[1] = -3.0e38f;
    lrun[0] = lrun[1] = 0.f;

    // ALiBi j-bias constants for this lane: bias(j) = mh2*j, j = 16ji+4g+r
    float jb[4], rb[4];
#pragma unroll
    for (int ji = 0; ji < 4; ++ji) jb[ji] = mh2 * (float)(ji * 16 + g * 4);
#pragma unroll
    for (int r = 0; r < 4; ++r) rb[r] = mh2 * (float)r;

    auto stageK = [&](int tile) {
        int j0 = tile * 64;
#pragma unroll
        for (int c = 0; c < 2; ++c) {
            int slot = c * 256 + t;
            int row = slot >> 3;
            int cs = (slot & 7) ^ (row & 7);
            __builtin_amdgcn_global_load_lds(
                (const AS1 void*)(Kp + (size_t)(j0 + row) * 64 + cs * 8),
                (AS3 void*)(&Kl[slot * 8]), 16, 0, 0);
        }
    };
    auto stageV = [&](int tile, int buf) {
        int j0 = tile * 64;
#pragma unroll
        for (int c = 0; c < 2; ++c) {
            int slot = c * 256 + t;
            int row = slot >> 3;
            int cs = (slot & 7) ^ (row & 7);
            __builtin_amdgcn_global_load_lds(
                (const AS1 void*)(Vp + (size_t)row * 2048 + j0 + cs * 8),
                (AS3 void*)(&Vl[buf][slot * 8]), 16, 0, 0);
        }
    };

    stageK(0);
    stageV(0, 0);
    bf16* Pw = Pl[wid];

    for (int tile = 0; tile < 32; ++tile) {
        __syncthreads();                 // b1: K[t],V[t] staged data drained
        const bf16* Vb = Vl[tile & 1];

        // S^T = K Q^T + bias (bias pre-loaded into the accumulator)
        float tb = mh2 * (float)(tile * 64);
        f32x4 sc[2][4];
#pragma unroll
        for (int ji = 0; ji < 4; ++ji) {
            float base = tb + jb[ji];
#pragma unroll
            for (int r = 0; r < 4; ++r) {
                float v = base + rb[r];
                sc[0][ji][r] = v;
                sc[1][ji][r] = v;
            }
        }
#pragma unroll
        for (int ji = 0; ji < 4; ++ji) {
#pragma unroll
            for (int kk = 0; kk < 2; ++kk) {
                int row = ji * 16 + l15;
                int c16 = (kk * 4 + g) ^ (row & 7);
                bf16x8 kf = *(const bf16x8*)(Kl + row * 64 + c16 * 8);
#pragma unroll
                for (int qi = 0; qi < 2; ++qi)
                    sc[qi][ji] = __builtin_amdgcn_mfma_f32_16x16x32_bf16(
                        kf, qf[qi][kk], sc[qi][ji], 0, 0, 0);
            }
        }
        __syncthreads();                 // b2: all waves done reading Kl
        if (tile + 1 < 32) {
            stageK(tile + 1);            // hidden under softmax+P+PV
            stageV(tile + 1, (tile + 1) & 1);
        }

        // in-lane partial max (16 j's per qi)
        float pmx[2];
#pragma unroll
        for (int qi = 0; qi < 2; ++qi) {
            float m0a = fmaxf(fmaxf(sc[qi][0][0], sc[qi][0][1]), fmaxf(sc[qi][0][2], sc[qi][0][3]));
            float m1a = fmaxf(fmaxf(sc[qi][1][0], sc[qi][1][1]), fmaxf(sc[qi][1][2], sc[qi][1][3]));
            float m2a = fmaxf(fmaxf(sc[qi][2][0], sc[qi][2][1]), fmaxf(sc[qi][2][2], sc[qi][2][3]));
            float m3a = fmaxf(fmaxf(sc[qi][3][0], sc[qi][3][1]), fmaxf(sc[qi][3][2], sc[qi][3][3]));
            pmx[qi] = fmaxf(fmaxf(m0a, m1a), fmaxf(m2a, m3a));
        }

        // defer-max: skip reduce+rescale when no partial max grew past thr
        int stable = (pmx[0] <= mrun[0] + 8.0f && pmx[1] <= mrun[1] + 8.0f) ? 1 : 0;
        if (!__all(stable)) {
            float corr[2];
#pragma unroll
            for (int qi = 0; qi < 2; ++qi) {
                float mx = pmx[qi];
                mx = fmaxf(mx, __shfl_xor(mx, 16));
                mx = fmaxf(mx, __shfl_xor(mx, 32));
                float mnew = fmaxf(mrun[qi], mx);
                corr[qi] = __builtin_amdgcn_exp2f(mrun[qi] - mnew);
                mrun[qi] = mnew;
                lrun[qi] *= corr[qi];
            }
            // bridge S-layout corr (q=l15) -> O-layout rows (q=g*4+r)
#pragma unroll
            for (int qi = 0; qi < 2; ++qi)
#pragma unroll
                for (int r = 0; r < 4; ++r) {
                    float cB = __shfl(corr[qi], g * 4 + r);
#pragma unroll
                    for (int di = 0; di < 4; ++di) oacc[qi][di][r] *= cB;
                }
        }

        // p = exp2(s - m); in-lane sum + 2-level quad reduce
#pragma unroll
        for (int qi = 0; qi < 2; ++qi) {
            float mq = mrun[qi];
            float s = 0.f;
#pragma unroll
            for (int ji = 0; ji < 4; ++ji)
#pragma unroll
                for (int r = 0; r < 4; ++r) {
                    float p = __builtin_amdgcn_exp2f(sc[qi][ji][r] - mq);
                    sc[qi][ji][r] = p;
                    s += p;
                }
            s += __shfl_xor(s, 16);
            s += __shfl_xor(s, 32);
            lrun[qi] += s;
        }

        // P -> wave-private LDS: contiguous-j b64 chunks, XOR-swizzled
#pragma unroll
        for (int qi = 0; qi < 2; ++qi) {
            int qloc = qi * 16 + l15;
            int base = qloc * 64;
            int swz = (qloc & 7) * 8;
#pragma unroll
            for (int ji = 0; ji < 4; ++ji) {
                bf16x4 pv;
                pv[0] = (bf16)sc[qi][ji][0];
                pv[1] = (bf16)sc[qi][ji][1];
                pv[2] = (bf16)sc[qi][ji][2];
                pv[3] = (bf16)sc[qi][ji][3];
                *(bf16x4*)(Pw + base + ((ji * 16 + g * 4) ^ swz)) = pv;
            }
        }

        // O += P @ V  (A-frag of P: row=q=l15, k=j)
#pragma unroll
        for (int kk = 0; kk < 2; ++kk) {
            bf16x8 pf[2];
#pragma unroll
            for (int qi = 0; qi < 2; ++qi) {
                int qloc = qi * 16 + l15;
                pf[qi] = *(const bf16x8*)(Pw + qloc * 64 + ((kk * 32 + g * 8) ^ ((qloc & 7) * 8)));
            }
#pragma unroll
            for (int di = 0; di < 4; ++di) {
                int row = di * 16 + l15;
                int c16 = (kk * 4 + g) ^ (row & 7);
                bf16x8 vf = *(const bf16x8*)(Vb + row * 64 + c16 * 8);
#pragma unroll
                for (int qi = 0; qi < 2; ++qi)
                    oacc[qi][di] = __builtin_amdgcn_mfma_f32_16x16x32_bf16(
                        pf[qi], vf, oacc[qi][di], 0, 0, 0);
            }
        }
    }

    // epilogue: O rows q=g*4+r (+16qi); lrun lives at lane l15=q (S-layout)
#pragma unroll
    for (int qi = 0; qi < 2; ++qi) {
#pragma unroll
        for (int r = 0; r < 4; ++r) {
            float lq = __shfl(lrun[qi], g * 4 + r);
            float inv = 1.0f / lq;
            int s = q0 + qi * 16 + g * 4 + r;
            float* op = out + ((size_t)b * 2048 + s) * 1024 + h * 64;
#pragma unroll
            for (int di = 0; di < 4; ++di)
                op[di * 16 + l15] = oacc[qi][di][r] * inv;
        }
    }
}

extern "C" void kernel_launch(void* const* d_in, const int* in_sizes, int n_in,
                              void* d_out, int out_size, void* d_ws, size_t ws_size,
                              hipStream_t stream) {
    (void)in_sizes; (void)n_in; (void)out_size; (void)ws_size;
    const float* x = (const float*)d_in[0];
    const float* w = (const float*)d_in[1];
    float* out = (float*)d_out;
    char* ws = (char*)d_ws;
    bf16* xb = (bf16*)(ws);
    bf16* wt = (bf16*)(ws + 16777216);
    bf16* kb = (bf16*)(ws + 23068672);
    bf16* qb = (bf16*)(ws + 39845888);
    bf16* vt = (bf16*)(ws + 56623104);

    cvt_x_kernel<<<4096, 256, 0, stream>>>(x, xb);
    cvt_w_kernel<<<dim3(96, 32), dim3(32, 8), 0, stream>>>(w, wt);
    gemm_kqv_kernel<<<1536, 256, 0, stream>>>(xb, wt, kb, qb, vt);
    attn_kernel<<<1024, 256, 0, stream>>>(qb, kb, vt, out);
}

// Round 10
// 304.161 us; speedup vs baseline: 2.2797x; 1.0249x over previous
//
#include <hip/hip_runtime.h>
#include <stdint.h>

typedef __bf16 bf16;
typedef __bf16 bf16x4 __attribute__((ext_vector_type(4)));
typedef __bf16 bf16x8 __attribute__((ext_vector_type(8)));
typedef float f32x4 __attribute__((ext_vector_type(4)));

#define AS1 __attribute__((address_space(1)))
#define AS3 __attribute__((address_space(3)))

// x: [4,2048,1024] f32, W: [1024,3072] f32, out: [4,2048,1024] f32
// ws: xb[8192][1024]bf16 @0; wt[3072][1024]bf16 @16777216; kb @23068672;
//     qb @39845888 (pre-scaled log2e/32); vt[64][64][2048] @56623104
// Base-2 softmax (log2e folded into qb + ALiBi slope).

__device__ __forceinline__ float f3(float a, float b, float c) {
    return fmaxf(fmaxf(a, b), c);      // encourages v_max3_f32
}

__global__ void cvt_x_kernel(const float* __restrict__ x, bf16* __restrict__ xb) {
    int i = blockIdx.x * 256 + threadIdx.x;
    const float4* x4 = (const float4*)x;
    float4 a = x4[i * 2];
    float4 b = x4[i * 2 + 1];
    bf16x8 o;
    o[0] = (bf16)a.x; o[1] = (bf16)a.y; o[2] = (bf16)a.z; o[3] = (bf16)a.w;
    o[4] = (bf16)b.x; o[5] = (bf16)b.y; o[6] = (bf16)b.z; o[7] = (bf16)b.w;
    *(bf16x8*)(xb + (size_t)i * 8) = o;
}

__global__ void cvt_w_kernel(const float* __restrict__ w, bf16* __restrict__ wt) {
    __shared__ float tile[32][33];
    int nt = blockIdx.x, kt = blockIdx.y;
    int tx = threadIdx.x, ty = threadIdx.y;
#pragma unroll
    for (int j = 0; j < 4; ++j)
        tile[ty + j * 8][tx] = w[(size_t)(kt * 32 + ty + j * 8) * 3072 + nt * 32 + tx];
    __syncthreads();
#pragma unroll
    for (int j = 0; j < 4; ++j)
        wt[(size_t)(nt * 32 + ty + j * 8) * 1024 + kt * 32 + tx] = (bf16)tile[tx][ty + j * 8];
}

// ---------------- GEMM: kqv = xb @ wt^T, scatter to kb/qb/vt ----------------
__global__ __launch_bounds__(256) void gemm_kqv_kernel(
    const bf16* __restrict__ xb, const bf16* __restrict__ wt,
    bf16* __restrict__ kb, bf16* __restrict__ qb, bf16* __restrict__ vt) {
    __shared__ bf16 As[2][128 * 32];
    __shared__ bf16 Bs[2][128 * 32];
    int bid = blockIdx.x;
    int bm = bid / 24, bn = bid % 24;
    int m0 = bm * 128, n0 = bn * 128;
    int t = threadIdx.x;
    int lane = t & 63, wid = t >> 6;
    int g = lane >> 4, l15 = lane & 15;
    int wr = wid >> 1, wc = wid & 1;

    f32x4 acc[4][4] = {};

    auto stageAB = [&](int ks, int buf) {
        int k0 = ks * 32;
#pragma unroll
        for (int c = 0; c < 2; ++c) {
            int slot = c * 256 + t;
            int row = slot >> 2, kk = (slot & 3) * 8;
            __builtin_amdgcn_global_load_lds(
                (const AS1 void*)(xb + (size_t)(m0 + row) * 1024 + k0 + kk),
                (AS3 void*)(&As[buf][slot * 8]), 16, 0, 0);
        }
#pragma unroll
        for (int c = 0; c < 2; ++c) {
            int slot = c * 256 + t;
            int row = slot >> 2, kk = (slot & 3) * 8;
            __builtin_amdgcn_global_load_lds(
                (const AS1 void*)(wt + (size_t)(n0 + row) * 1024 + k0 + kk),
                (AS3 void*)(&Bs[buf][slot * 8]), 16, 0, 0);
        }
    };

    stageAB(0, 0);
    for (int ks = 0; ks < 32; ++ks) {
        __syncthreads();
        if (ks + 1 < 32) stageAB(ks + 1, (ks + 1) & 1);
        const bf16* Ab = As[ks & 1];
        const bf16* Bb = Bs[ks & 1];
        bf16x8 af[4], bfr[4];
#pragma unroll
        for (int mi = 0; mi < 4; ++mi)
            af[mi] = *(const bf16x8*)(Ab + (wr * 64 + mi * 16 + l15) * 32 + g * 8);
#pragma unroll
        for (int ni = 0; ni < 4; ++ni)
            bfr[ni] = *(const bf16x8*)(Bb + (wc * 64 + ni * 16 + l15) * 32 + g * 8);
#pragma unroll
        for (int mi = 0; mi < 4; ++mi)
#pragma unroll
            for (int ni = 0; ni < 4; ++ni)
                acc[mi][ni] = __builtin_amdgcn_mfma_f32_16x16x32_bf16(
                    af[mi], bfr[ni], acc[mi][ni], 0, 0, 0);
    }

    // epilogue: h = hbase+wc (uniform per wc), d = ni*16+l15; block never
    // straddles a batch boundary (m0 multiple of 128, 2048%128==0).
    int tsel = n0 >> 10;
    int hbase = (n0 >> 6) & 15;
    int bidx = m0 >> 11;
    int m0b = (m0 & 2047) + wr * 64 + g * 4;
    int bh = bidx * 16 + hbase + wc;
    if (tsel == 2) {
        // vt[bh][d][s]: 4 consecutive s per lane -> bf16x4 stores (4x fewer)
#pragma unroll
        for (int ni = 0; ni < 4; ++ni) {
            int d = ni * 16 + l15;
            bf16* vbase = vt + ((size_t)bh * 64 + d) * 2048 + m0b;
#pragma unroll
            for (int mi = 0; mi < 4; ++mi) {
                bf16x4 pv;
                pv[0] = (bf16)acc[mi][ni][0];
                pv[1] = (bf16)acc[mi][ni][1];
                pv[2] = (bf16)acc[mi][ni][2];
                pv[3] = (bf16)acc[mi][ni][3];
                *(bf16x4*)(vbase + mi * 16) = pv;
            }
        }
    } else {
        bf16* dst = (tsel == 0) ? kb : qb;
        float sc = (tsel == 0) ? 1.0f : 0.0450842503f;  // log2e/32 for q
#pragma unroll
        for (int mi = 0; mi < 4; ++mi)
#pragma unroll
            for (int ni = 0; ni < 4; ++ni) {
                int d = ni * 16 + l15;
#pragma unroll
                for (int r = 0; r < 4; ++r) {
                    int s = m0b + mi * 16 + r;
                    dst[((size_t)bh * 2048 + s) * 64 + d] = (bf16)(acc[mi][ni][r] * sc);
                }
            }
    }
}

// ---------------- Flash attention with ALiBi (base-2, swapped QK^T) ----------
// S^T = mfma(K, Q): lane owns one q-row (q=l15) x 16 j's per qi.
// C-init = bias - mrun (sentinel -1e4): stable tiles exp2 sc directly (no sub).
// LDS 40KB; no min-waves bound (r6 spill lesson).
__global__ __launch_bounds__(256) void attn_kernel(
    const bf16* __restrict__ qb, const bf16* __restrict__ kb,
    const bf16* __restrict__ vt, float* __restrict__ out) {
    __shared__ bf16 Kl[64 * 64];
    __shared__ bf16 Vl[2][64 * 64];
    __shared__ bf16 Pl[4][32 * 64];
    int bid = blockIdx.x;
    int bh = bid >> 4, qt = bid & 15;
    int b = bh >> 4, h = bh & 15;
    int t = threadIdx.x, lane = t & 63, wid = t >> 6;
    int g = lane >> 4, l15 = lane & 15;
    int q0 = qt * 128 + wid * 32;
    float mh2 = exp2f(-0.5f * (float)(h + 1)) * 1.44269504f;

    const bf16* Qp = qb + ((size_t)bh * 2048 + q0) * 64;
    const bf16* Kp = kb + (size_t)bh * 2048 * 64;
    const bf16* Vp = vt + (size_t)bh * 64 * 2048;

    bf16x8 qf[2][2];
#pragma unroll
    for (int qi = 0; qi < 2; ++qi)
#pragma unroll
        for (int kk = 0; kk < 2; ++kk)
            qf[qi][kk] = *(const bf16x8*)(Qp + (size_t)(qi * 16 + l15) * 64 + kk * 32 + g * 8);

    f32x4 oacc[2][4] = {};
    float mrun[2], lrun[2];
    mrun[0] = mrun[1] = -10000.0f;   // moderate sentinel: f32-exact folding
    lrun[0] = lrun[1] = 0.f;

    // bias(j) = mh2*j, j = 16ji + 4g + r
    float jb[4], rb[4];
#pragma unroll
    for (int ji = 0; ji < 4; ++ji) jb[ji] = mh2 * (float)(ji * 16 + g * 4);
#pragma unroll
    for (int r = 0; r < 4; ++r) rb[r] = mh2 * (float)r;

    auto stageK = [&](int tile) {
        int j0 = tile * 64;
#pragma unroll
        for (int c = 0; c < 2; ++c) {
            int slot = c * 256 + t;
            int row = slot >> 3;
            int cs = (slot & 7) ^ (row & 7);
            __builtin_amdgcn_global_load_lds(
                (const AS1 void*)(Kp + (size_t)(j0 + row) * 64 + cs * 8),
                (AS3 void*)(&Kl[slot * 8]), 16, 0, 0);
        }
    };
    auto stageV = [&](int tile, int buf) {
        int j0 = tile * 64;
#pragma unroll
        for (int c = 0; c < 2; ++c) {
            int slot = c * 256 + t;
            int row = slot >> 3;
            int cs = (slot & 7) ^ (row & 7);
            __builtin_amdgcn_global_load_lds(
                (const AS1 void*)(Vp + (size_t)row * 2048 + j0 + cs * 8),
                (AS3 void*)(&Vl[buf][slot * 8]), 16, 0, 0);
        }
    };

    stageK(0);
    stageV(0, 0);
    bf16* Pw = Pl[wid];

    for (int tile = 0; tile < 32; ++tile) {
        __syncthreads();                 // b1: K[t],V[t] staged data drained
        const bf16* Vb = Vl[tile & 1];

        // C-init = bias - mrun; after MFMA, sc = logit - m_old
        float tb = mh2 * (float)(tile * 64);
        f32x4 sc[2][4];
#pragma unroll
        for (int qi = 0; qi < 2; ++qi) {
            float bq = tb - mrun[qi];
#pragma unroll
            for (int ji = 0; ji < 4; ++ji) {
                float base = bq + jb[ji];
#pragma unroll
                for (int r = 0; r < 4; ++r) sc[qi][ji][r] = base + rb[r];
            }
        }
#pragma unroll
        for (int ji = 0; ji < 4; ++ji) {
#pragma unroll
            for (int kk = 0; kk < 2; ++kk) {
                int row = ji * 16 + l15;
                int c16 = (kk * 4 + g) ^ (row & 7);
                bf16x8 kf = *(const bf16x8*)(Kl + row * 64 + c16 * 8);
#pragma unroll
                for (int qi = 0; qi < 2; ++qi)
                    sc[qi][ji] = __builtin_amdgcn_mfma_f32_16x16x32_bf16(
                        kf, qf[qi][kk], sc[qi][ji], 0, 0, 0);
            }
        }
        __syncthreads();                 // b2: all waves done reading Kl
        if (tile + 1 < 32) {
            stageK(tile + 1);            // hidden under softmax+P+PV
            stageV(tile + 1, (tile + 1) & 1);
        }

        // in-lane partial max (relative to m_old), max3 tree
        float pmx[2];
#pragma unroll
        for (int qi = 0; qi < 2; ++qi) {
            float a0 = f3(sc[qi][0][0], sc[qi][0][1], sc[qi][0][2]);
            float a1 = f3(sc[qi][0][3], sc[qi][1][0], sc[qi][1][1]);
            float a2 = f3(sc[qi][1][2], sc[qi][1][3], sc[qi][2][0]);
            float a3 = f3(sc[qi][2][1], sc[qi][2][2], sc[qi][2][3]);
            float a4 = f3(sc[qi][3][0], sc[qi][3][1], sc[qi][3][2]);
            float a5 = fmaxf(sc[qi][3][3], f3(a0, a1, a2));
            pmx[qi] = f3(a3, a4, a5);
        }

        // defer-max: stable iff every row's growth <= 8 (sc already rel m_old)
        int stable = (pmx[0] <= 8.0f && pmx[1] <= 8.0f) ? 1 : 0;
        if (!__all(stable)) {
            float dm[2], corr[2];
#pragma unroll
            for (int qi = 0; qi < 2; ++qi) {
                float mx = pmx[qi];
                mx = fmaxf(mx, __shfl_xor(mx, 16));
                mx = fmaxf(mx, __shfl_xor(mx, 32));
                float d = fmaxf(mx, 0.0f);          // delta = mnew - m_old
                dm[qi] = d;
                corr[qi] = __builtin_amdgcn_exp2f(-d);
                mrun[qi] += d;
                lrun[qi] *= corr[qi];
            }
            // re-base sc to new max
#pragma unroll
            for (int qi = 0; qi < 2; ++qi)
#pragma unroll
                for (int ji = 0; ji < 4; ++ji)
#pragma unroll
                    for (int r = 0; r < 4; ++r) sc[qi][ji][r] -= dm[qi];
            // bridge S-layout corr (q=l15) -> O-layout rows (q=g*4+r)
#pragma unroll
            for (int qi = 0; qi < 2; ++qi)
#pragma unroll
                for (int r = 0; r < 4; ++r) {
                    float cB = __shfl(corr[qi], g * 4 + r);
#pragma unroll
                    for (int di = 0; di < 4; ++di) oacc[qi][di][r] *= cB;
                }
        }

        // p = exp2(sc) directly; in-lane sum + 2 shfl_xor
#pragma unroll
        for (int qi = 0; qi < 2; ++qi) {
            float s = 0.f;
#pragma unroll
            for (int ji = 0; ji < 4; ++ji)
#pragma unroll
                for (int r = 0; r < 4; ++r) {
                    float p = __builtin_amdgcn_exp2f(sc[qi][ji][r]);
                    sc[qi][ji][r] = p;
                    s += p;
                }
            s += __shfl_xor(s, 16);
            s += __shfl_xor(s, 32);
            lrun[qi] += s;
        }

        // P -> wave-private LDS: contiguous-j b64 chunks, XOR-swizzled
#pragma unroll
        for (int qi = 0; qi < 2; ++qi) {
            int qloc = qi * 16 + l15;
            int base = qloc * 64;
            int swz = (qloc & 7) * 8;
#pragma unroll
            for (int ji = 0; ji < 4; ++ji) {
                bf16x4 pv;
                pv[0] = (bf16)sc[qi][ji][0];
                pv[1] = (bf16)sc[qi][ji][1];
                pv[2] = (bf16)sc[qi][ji][2];
                pv[3] = (bf16)sc[qi][ji][3];
                *(bf16x4*)(Pw + base + ((ji * 16 + g * 4) ^ swz)) = pv;
            }
        }

        // O += P @ V  (A-frag of P: row=q=l15, k=j)
#pragma unroll
        for (int kk = 0; kk < 2; ++kk) {
            bf16x8 pf[2];
#pragma unroll
            for (int qi = 0; qi < 2; ++qi) {
                int qloc = qi * 16 + l15;
                pf[qi] = *(const bf16x8*)(Pw + qloc * 64 + ((kk * 32 + g * 8) ^ ((qloc & 7) * 8)));
            }
#pragma unroll
            for (int di = 0; di < 4; ++di) {
                int row = di * 16 + l15;
                int c16 = (kk * 4 + g) ^ (row & 7);
                bf16x8 vf = *(const bf16x8*)(Vb + row * 64 + c16 * 8);
#pragma unroll
                for (int qi = 0; qi < 2; ++qi)
                    oacc[qi][di] = __builtin_amdgcn_mfma_f32_16x16x32_bf16(
                        pf[qi], vf, oacc[qi][di], 0, 0, 0);
            }
        }
    }

    // epilogue: O rows q=g*4+r (+16qi); lrun lives at lane l15=q (S-layout)
#pragma unroll
    for (int qi = 0; qi < 2; ++qi) {
#pragma unroll
        for (int r = 0; r < 4; ++r) {
            float lq = __shfl(lrun[qi], g * 4 + r);
            float inv = 1.0f / lq;
            int s = q0 + qi * 16 + g * 4 + r;
            float* op = out + ((size_t)b * 2048 + s) * 1024 + h * 64;
#pragma unroll
            for (int di = 0; di < 4; ++di)
                op[di * 16 + l15] = oacc[qi][di][r] * inv;
        }
    }
}

extern "C" void kernel_launch(void* const* d_in, const int* in_sizes, int n_in,
                              void* d_out, int out_size, void* d_ws, size_t ws_size,
                              hipStream_t stream) {
    (void)in_sizes; (void)n_in; (void)out_size; (void)ws_size;
    const float* x = (const float*)d_in[0];
    const float* w = (const float*)d_in[1];
    float* out = (float*)d_out;
    char* ws = (char*)d_ws;
    bf16* xb = (bf16*)(ws);
    bf16* wt = (bf16*)(ws + 16777216);
    bf16* kb = (bf16*)(ws + 23068672);
    bf16* qb = (bf16*)(ws + 39845888);
    bf16* vt = (bf16*)(ws + 56623104);

    cvt_x_kernel<<<4096, 256, 0, stream>>>(x, xb);
    cvt_w_kernel<<<dim3(96, 32), dim3(32, 8), 0, stream>>>(w, wt);
    gemm_kqv_kernel<<<1536, 256, 0, stream>>>(xb, wt, kb, qb, vt);
    attn_kernel<<<1024, 256, 0, stream>>>(qb, kb, vt, out);
}